// Round 1
// baseline (324.786 us; speedup 1.0000x reference)
//
#include <hip/hip_runtime.h>

#define BB 8
#define CC 128
#define OO 128
#define HH 64
#define WW 64
#define HW (HH*WW)

// ---------------------------------------------------------------------------
// One-time weight relayouts:
//   wt[kk][c][o]       <- w_dconv[o][c][kk]   (coalesced LDS staging in deform)
//   w_off_t[c][ky][kx][oc] <- w_off[oc][c][ky][kx] (contiguous scalar loads)
// ---------------------------------------------------------------------------
__global__ __launch_bounds__(256) void transform_weights(
    const float* __restrict__ w_dconv,
    const float* __restrict__ w_off,
    float* __restrict__ wt,
    float* __restrict__ w_off_t)
{
    int idx = blockIdx.x * 256 + threadIdx.x;
    if (idx < 9 * 128 * 128) {
        int o  = idx & 127;
        int c  = (idx >> 7) & 127;
        int kk = idx >> 14;
        wt[idx] = w_dconv[(o * 128 + c) * 9 + kk];
    }
    if (idx < 128 * 9 * 18) {
        int oc = idx % 18;
        int r  = idx / 18;            // r = c*9 + ky*3 + kx
        w_off_t[idx] = w_off[oc * 1152 + r];
    }
}

// ---------------------------------------------------------------------------
// BN + ReLU, emit h in NCHW (offset conv) and NHWC (deform gathers).
// LDS transpose, stride 129 to keep banks conflict-free.
// grid = B*H (512), block = 256
// ---------------------------------------------------------------------------
__global__ __launch_bounds__(256) void bn_relu_transpose(
    const float* __restrict__ x,
    const float* __restrict__ gamma, const float* __restrict__ beta,
    const float* __restrict__ mean,  const float* __restrict__ var,
    float* __restrict__ h_nchw, float* __restrict__ h_nhwc)
{
    __shared__ float tile[64 * 129];
    int blk = blockIdx.x;
    int b = blk >> 6, y = blk & 63;
    int tid = threadIdx.x;
    int xx = tid & 63, c0 = tid >> 6;            // c0 uniform per wave
    size_t base_b = (size_t)b * (CC * HW) + (size_t)y * WW;

    for (int i = 0; i < 32; ++i) {
        int c = c0 + (i << 2);
        float inv = gamma[c] * rsqrtf(var[c] + 1e-5f);
        size_t a = base_b + (size_t)c * HW + xx;
        float v = fmaxf((x[a] - mean[c]) * inv + beta[c], 0.0f);
        h_nchw[a] = v;
        tile[xx * 129 + c] = v;
    }
    __syncthreads();
    int c = tid & 127, xh = tid >> 7;
    size_t ob = (((size_t)b * HH + y) * WW) * CC;
    for (int i = 0; i < 32; ++i) {
        int xw = (i << 1) + xh;
        h_nhwc[ob + (size_t)xw * CC + c] = tile[xw * 129 + c];
    }
}

// ---------------------------------------------------------------------------
// 3x3 conv, 128 -> 18 channels. Block per (b,y): 64x lanes x 4 c-quarters,
// 18 accumulators per thread, wave-uniform scalar weight loads, LDS reduce.
// grid = B*H (512), block = 256
// ---------------------------------------------------------------------------
__global__ __launch_bounds__(256) void offset_conv(
    const float* __restrict__ h,        // NCHW
    const float* __restrict__ w_off_t,  // [c][ky][kx][18]
    const float* __restrict__ b_off,
    float* __restrict__ offs)           // [b][18][y][x]
{
    __shared__ float part[4 * 18 * 64];
    int blk = blockIdx.x;
    int b = blk >> 6, y = blk & 63;
    int tid = threadIdx.x;
    int xx = tid & 63, cq = tid >> 6;            // cq uniform per wave

    float acc[18];
    #pragma unroll
    for (int i = 0; i < 18; ++i) acc[i] = 0.f;

    const float* hb = h + (size_t)b * CC * HW;
    for (int ci = 0; ci < 32; ++ci) {
        int c = cq * 32 + ci;
        const float* hc = hb + (size_t)c * HW;
        #pragma unroll
        for (int ky = 0; ky < 3; ++ky) {
            int yy = y + ky - 1;
            if (yy < 0 || yy >= HH) continue;    // wave-uniform branch
            const float* hr = hc + yy * WW;
            float vm = (xx > 0)  ? hr[xx - 1] : 0.f;
            float v0 = hr[xx];
            float vp = (xx < 63) ? hr[xx + 1] : 0.f;
            const float* wrow = w_off_t + (c * 3 + ky) * 3 * 18;
            #pragma unroll
            for (int oc = 0; oc < 18; ++oc) acc[oc] = fmaf(vm, wrow[oc],      acc[oc]);
            #pragma unroll
            for (int oc = 0; oc < 18; ++oc) acc[oc] = fmaf(v0, wrow[18 + oc], acc[oc]);
            #pragma unroll
            for (int oc = 0; oc < 18; ++oc) acc[oc] = fmaf(vp, wrow[36 + oc], acc[oc]);
        }
    }
    #pragma unroll
    for (int oc = 0; oc < 18; ++oc) part[(cq * 18 + oc) * 64 + xx] = acc[oc];
    __syncthreads();

    size_t ob = (size_t)b * 18 * HW + (size_t)y * WW;
    for (int e = tid; e < 18 * 64; e += 256) {
        int oc = e >> 6, xw = e & 63;
        float v = part[e] + part[1152 + e] + part[2304 + e] + part[3456 + e] + b_off[oc];
        offs[ob + (size_t)oc * HW + xw] = v;
    }
}

// ---------------------------------------------------------------------------
// Deformable conv. Block per (b,y) row.
// Phase 0: 576 bilinear param sets (4 masked weights + 4 clamped tap offsets).
// K-loop over (kk, 32-channel chunk): stage v[32][64] (4 coalesced NHWC
// gathers each) and w[32][128] in LDS; 4x x 8o register-blocked FMA with
// float4 LDS reads. LDS ~44KB -> 2 blocks/CU.
// grid = B*H (512), block = 256
// ---------------------------------------------------------------------------
__global__ __launch_bounds__(256, 2) void deform_conv(
    const float* __restrict__ h,       // NHWC
    const float* __restrict__ offs,    // [b][18][y][x]
    const float* __restrict__ wt,      // [kk][c][o]
    const float* __restrict__ b_dconv,
    float* __restrict__ out)           // NCHW
{
    __shared__ float pw[576 * 4];
    __shared__ int   pidx[576 * 4];
    __shared__ __align__(16) float vtile[32 * 68];
    __shared__ __align__(16) float wtile[32 * 132];

    int blk = blockIdx.x;
    int b = blk >> 6, y = blk & 63;
    int tid = threadIdx.x;

    const float* hb = h + (size_t)b * HW * CC;
    size_t offbase = (size_t)b * 18 * HW + (size_t)y * WW;

    // ---- phase 0: bilinear params for all (kk, x) of this row ----
    for (int e = tid; e < 576; e += 256) {
        int kk = e >> 6, xx = e & 63;
        float dy = offs[offbase + (size_t)(2 * kk) * HW + xx];
        float dx = offs[offbase + (size_t)(2 * kk + 1) * HW + xx];
        float py = dy + (float)y + (float)(kk / 3 - 1);
        float px = dx + (float)xx + (float)(kk % 3 - 1);
        float fy = floorf(py), fx = floorf(px);
        int y0 = (int)fy, x0 = (int)fx;
        float wy = py - fy, wx = px - fx;
        int y1 = y0 + 1, x1 = x0 + 1;
        bool vy0 = (y0 >= 0) && (y0 < HH);
        bool vy1 = (y1 >= 0) && (y1 < HH);
        bool vx0 = (x0 >= 0) && (x0 < WW);
        bool vx1 = (x1 >= 0) && (x1 < WW);
        int yc0 = min(max(y0, 0), HH - 1), yc1 = min(max(y1, 0), HH - 1);
        int xc0 = min(max(x0, 0), WW - 1), xc1 = min(max(x1, 0), WW - 1);
        pw[e * 4 + 0] = (vy0 && vx0) ? (1.f - wy) * (1.f - wx) : 0.f;
        pw[e * 4 + 1] = (vy0 && vx1) ? (1.f - wy) * wx         : 0.f;
        pw[e * 4 + 2] = (vy1 && vx0) ? wy * (1.f - wx)         : 0.f;
        pw[e * 4 + 3] = (vy1 && vx1) ? wy * wx                 : 0.f;
        pidx[e * 4 + 0] = (yc0 * WW + xc0) * CC;
        pidx[e * 4 + 1] = (yc0 * WW + xc1) * CC;
        pidx[e * 4 + 2] = (yc1 * WW + xc0) * CC;
        pidx[e * 4 + 3] = (yc1 * WW + xc1) * CC;
    }

    int xg = tid & 15, og = tid >> 4;      // MAC mapping: x = xg*4.., o = og*8..
    int cl = tid & 31, xs8 = tid >> 5;     // staging mapping
    float acc[4][8];
    #pragma unroll
    for (int i = 0; i < 4; ++i)
        #pragma unroll
        for (int j = 0; j < 8; ++j) acc[i][j] = 0.f;

    for (int kk = 0; kk < 9; ++kk) {
        for (int ccb = 0; ccb < 4; ++ccb) {
            __syncthreads();
            // stage w chunk: 32c x 128o, coalesced
            const float* wsrc = wt + ((size_t)kk * CC + ccb * 32) * OO;
            #pragma unroll
            for (int j = 0; j < 16; ++j) {
                int idx = j * 256 + tid;
                int c_l = idx >> 7, oo = idx & 127;
                wtile[c_l * 132 + oo] = wsrc[c_l * OO + oo];
            }
            // stage v chunk: 32c x 64x; 32 lanes sweep contiguous c per tap
            int cg = ccb * 32 + cl;
            #pragma unroll
            for (int j = 0; j < 8; ++j) {
                int xx = xs8 * 8 + j;
                int e = (kk << 6) + xx;
                float v = pw[e * 4 + 0] * hb[pidx[e * 4 + 0] + cg]
                        + pw[e * 4 + 1] * hb[pidx[e * 4 + 1] + cg]
                        + pw[e * 4 + 2] * hb[pidx[e * 4 + 2] + cg]
                        + pw[e * 4 + 3] * hb[pidx[e * 4 + 3] + cg];
                vtile[cl * 68 + xx] = v;
            }
            __syncthreads();
            // register-blocked MAC: 32 c-steps x (4x * 8o)
            #pragma unroll
            for (int c = 0; c < 32; ++c) {
                float4 v4 = *(const float4*)&vtile[c * 68 + xg * 4];
                float4 wa = *(const float4*)&wtile[c * 132 + og * 8];
                float4 wb = *(const float4*)&wtile[c * 132 + og * 8 + 4];
                float av[4] = {v4.x, v4.y, v4.z, v4.w};
                float aw[8] = {wa.x, wa.y, wa.z, wa.w, wb.x, wb.y, wb.z, wb.w};
                #pragma unroll
                for (int i = 0; i < 4; ++i)
                    #pragma unroll
                    for (int jj = 0; jj < 8; ++jj)
                        acc[i][jj] = fmaf(av[i], aw[jj], acc[i][jj]);
            }
        }
    }

    size_t ob = (size_t)b * OO * HW + (size_t)y * WW;
    #pragma unroll
    for (int jj = 0; jj < 8; ++jj) {
        int o = og * 8 + jj;
        float bias = b_dconv[o];
        float4 r;
        r.x = acc[0][jj] + bias;
        r.y = acc[1][jj] + bias;
        r.z = acc[2][jj] + bias;
        r.w = acc[3][jj] + bias;
        *(float4*)&out[ob + (size_t)o * HW + xg * 4] = r;
    }
}

// ---------------------------------------------------------------------------
extern "C" void kernel_launch(void* const* d_in, const int* in_sizes, int n_in,
                              void* d_out, int out_size, void* d_ws, size_t ws_size,
                              hipStream_t stream)
{
    const float* x       = (const float*)d_in[0];
    const float* gamma   = (const float*)d_in[1];
    const float* beta    = (const float*)d_in[2];
    const float* mean    = (const float*)d_in[3];
    const float* var     = (const float*)d_in[4];
    const float* w_off   = (const float*)d_in[5];
    const float* b_off   = (const float*)d_in[6];
    const float* w_dconv = (const float*)d_in[7];
    const float* b_dconv = (const float*)d_in[8];
    float* out = (float*)d_out;

    float* ws      = (float*)d_ws;
    float* h_nchw  = ws;                    // 4,194,304 f
    float* h_nhwc  = h_nchw + 4194304;      // 4,194,304 f
    float* offs    = h_nhwc + 4194304;      //   589,824 f
    float* wt      = offs + 589824;         //   147,456 f
    float* w_off_t = wt + 147456;           //    20,736 f  -> total ~36.6 MB

    transform_weights<<<576, 256, 0, stream>>>(w_dconv, w_off, wt, w_off_t);
    bn_relu_transpose<<<512, 256, 0, stream>>>(x, gamma, beta, mean, var, h_nchw, h_nhwc);
    offset_conv<<<512, 256, 0, stream>>>(h_nchw, w_off_t, b_off, offs);
    deform_conv<<<512, 256, 0, stream>>>(h_nhwc, offs, wt, b_dconv, out);
}

// Round 2
// 178.343 us; speedup vs baseline: 1.8211x; 1.8211x over previous
//
#include <hip/hip_runtime.h>

#define BB 8
#define CC 128
#define OO 128
#define HH 64
#define WW 64
#define HW (HH*WW)

typedef __attribute__((ext_vector_type(8))) __bf16 bf16x8;
typedef __attribute__((ext_vector_type(4))) __bf16 bf16x4;
typedef __attribute__((ext_vector_type(4))) float  f32x4;

// ---------------------------------------------------------------------------
// One-time weight relayouts:
//   wt_bf[kk][o][c]        (bf16) <- w_dconv[o][c][kk]   (K-contiguous for MFMA frags)
//   w_off_t[c][ky][kx][oc] (f32)  <- w_off[oc][c][ky][kx] (uniform scalar loads)
// ---------------------------------------------------------------------------
__global__ __launch_bounds__(256) void transform_weights(
    const float* __restrict__ w_dconv,
    const float* __restrict__ w_off,
    __bf16* __restrict__ wt_bf,
    float* __restrict__ w_off_t)
{
    int idx = blockIdx.x * 256 + threadIdx.x;
    if (idx < 9 * 128 * 128) {
        int c  = idx & 127;
        int o  = (idx >> 7) & 127;
        int kk = idx >> 14;
        wt_bf[idx] = (__bf16)w_dconv[(o * 128 + c) * 9 + kk];
    }
    if (idx < 128 * 9 * 18) {
        int oc = idx % 18;
        int r  = idx / 18;            // r = c*9 + ky*3 + kx
        w_off_t[idx] = w_off[oc * 1152 + r];
    }
}

// ---------------------------------------------------------------------------
// BN + ReLU, emit h in NCHW (offset conv) and NHWC fp32 (deform gathers).
// ---------------------------------------------------------------------------
__global__ __launch_bounds__(256) void bn_relu_transpose(
    const float* __restrict__ x,
    const float* __restrict__ gamma, const float* __restrict__ beta,
    const float* __restrict__ mean,  const float* __restrict__ var,
    float* __restrict__ h_nchw, float* __restrict__ h_nhwc)
{
    __shared__ float tile[64 * 129];
    int blk = blockIdx.x;
    int b = blk >> 6, y = blk & 63;
    int tid = threadIdx.x;
    int xx = tid & 63, c0 = tid >> 6;
    size_t base_b = (size_t)b * (CC * HW) + (size_t)y * WW;

    for (int i = 0; i < 32; ++i) {
        int c = c0 + (i << 2);
        float inv = gamma[c] * rsqrtf(var[c] + 1e-5f);
        size_t a = base_b + (size_t)c * HW + xx;
        float v = fmaxf((x[a] - mean[c]) * inv + beta[c], 0.0f);
        h_nchw[a] = v;
        tile[xx * 129 + c] = v;
    }
    __syncthreads();
    int c = tid & 127, xh = tid >> 7;
    size_t ob = (((size_t)b * HH + y) * WW) * CC;
    for (int i = 0; i < 32; ++i) {
        int xw = (i << 1) + xh;
        h_nhwc[ob + (size_t)xw * CC + c] = tile[xw * 129 + c];
    }
}

// ---------------------------------------------------------------------------
// 3x3 conv, 128 -> 18 channels. readfirstlane(cq) makes the weight pointer
// provably wave-uniform -> s_load on the scalar pipe -> FMA-bound.
// ---------------------------------------------------------------------------
__global__ __launch_bounds__(256) void offset_conv(
    const float* __restrict__ h,        // NCHW
    const float* __restrict__ w_off_t,  // [c][ky][kx][18]
    const float* __restrict__ b_off,
    float* __restrict__ offs)           // [b][18][y][x]
{
    __shared__ float part[4 * 18 * 64];
    int blk = blockIdx.x;
    int b = blk >> 6, y = blk & 63;
    int tid = threadIdx.x;
    int xx = tid & 63;
    int cq = __builtin_amdgcn_readfirstlane(tid >> 6);   // wave-uniform, provably

    float acc[18];
    #pragma unroll
    for (int i = 0; i < 18; ++i) acc[i] = 0.f;

    const float* hb = h + (size_t)b * CC * HW;
    for (int ci = 0; ci < 32; ++ci) {
        int c = cq * 32 + ci;
        const float* hc = hb + (size_t)c * HW;
        #pragma unroll
        for (int ky = 0; ky < 3; ++ky) {
            int yy = y + ky - 1;
            if (yy < 0 || yy >= HH) continue;    // wave-uniform branch
            const float* hr = hc + yy * WW;
            float vm = (xx > 0)  ? hr[xx - 1] : 0.f;
            float v0 = hr[xx];
            float vp = (xx < 63) ? hr[xx + 1] : 0.f;
            const float* wrow = w_off_t + (c * 3 + ky) * 3 * 18;
            #pragma unroll
            for (int oc = 0; oc < 18; ++oc) acc[oc] = fmaf(vm, wrow[oc],      acc[oc]);
            #pragma unroll
            for (int oc = 0; oc < 18; ++oc) acc[oc] = fmaf(v0, wrow[18 + oc], acc[oc]);
            #pragma unroll
            for (int oc = 0; oc < 18; ++oc) acc[oc] = fmaf(vp, wrow[36 + oc], acc[oc]);
        }
    }
    #pragma unroll
    for (int oc = 0; oc < 18; ++oc) part[(cq * 18 + oc) * 64 + xx] = acc[oc];
    __syncthreads();

    size_t ob = (size_t)b * 18 * HW + (size_t)y * WW;
    for (int e = tid; e < 18 * 64; e += 256) {
        int oc = e >> 6, xw = e & 63;
        float v = part[e] + part[1152 + e] + part[2304 + e] + part[3456 + e] + b_off[oc];
        offs[ob + (size_t)oc * HW + xw] = v;
    }
}

// ---------------------------------------------------------------------------
// Deformable conv via bf16 MFMA. Block per (b,y) row = 64x128x1152 GEMM.
// Phase 0: 576 bilinear param sets into LDS.
// Per kk chunk (K=128c): stage w[128o][128c]+v[64x][128c] bf16 in LDS
// (stride 136: 2-way bank conflicts only), 4 K-steps x 8 mfma/wave.
// Frag layouts (verified, guide §3): A/B [idx=lane&15][k=quad*8+j],
// D row(m)=quad*4+reg, col(n)=lane&15.
// LDS 70.6 KB -> 2 blocks/CU.
// ---------------------------------------------------------------------------
__global__ __launch_bounds__(256, 2) void deform_conv_mfma(
    const float* __restrict__ h,       // NHWC fp32
    const float* __restrict__ offs,    // [b][18][y][x]
    const __bf16* __restrict__ wt,     // [kk][o][c] bf16
    const float* __restrict__ b_dconv,
    float* __restrict__ out)           // NCHW fp32
{
    __shared__ float pw[576 * 4];
    __shared__ int   pidx[576 * 4];
    __shared__ __align__(16) __bf16 vt[64 * 136];
    __shared__ __align__(16) __bf16 wl[128 * 136];

    int blk = blockIdx.x;
    int b = blk >> 6, y = blk & 63;
    int tid = threadIdx.x;

    const float* hb = h + (size_t)b * HW * CC;
    size_t offbase = (size_t)b * 18 * HW + (size_t)y * WW;

    // ---- phase 0: bilinear params (masked weights + clamped tap offsets) ----
    for (int e = tid; e < 576; e += 256) {
        int kk = e >> 6, xx = e & 63;
        float dy = offs[offbase + (size_t)(2 * kk) * HW + xx];
        float dx = offs[offbase + (size_t)(2 * kk + 1) * HW + xx];
        float py = dy + (float)y + (float)(kk / 3 - 1);
        float px = dx + (float)xx + (float)(kk % 3 - 1);
        float fy = floorf(py), fx = floorf(px);
        int y0 = (int)fy, x0 = (int)fx;
        float wy = py - fy, wx = px - fx;
        int y1 = y0 + 1, x1 = x0 + 1;
        bool vy0 = (y0 >= 0) && (y0 < HH);
        bool vy1 = (y1 >= 0) && (y1 < HH);
        bool vx0 = (x0 >= 0) && (x0 < WW);
        bool vx1 = (x1 >= 0) && (x1 < WW);
        int yc0 = min(max(y0, 0), HH - 1), yc1 = min(max(y1, 0), HH - 1);
        int xc0 = min(max(x0, 0), WW - 1), xc1 = min(max(x1, 0), WW - 1);
        pw[e * 4 + 0] = (vy0 && vx0) ? (1.f - wy) * (1.f - wx) : 0.f;
        pw[e * 4 + 1] = (vy0 && vx1) ? (1.f - wy) * wx         : 0.f;
        pw[e * 4 + 2] = (vy1 && vx0) ? wy * (1.f - wx)         : 0.f;
        pw[e * 4 + 3] = (vy1 && vx1) ? wy * wx                 : 0.f;
        pidx[e * 4 + 0] = (yc0 * WW + xc0) * CC;
        pidx[e * 4 + 1] = (yc0 * WW + xc1) * CC;
        pidx[e * 4 + 2] = (yc1 * WW + xc0) * CC;
        pidx[e * 4 + 3] = (yc1 * WW + xc1) * CC;
    }

    int lane = tid & 63;
    int wv   = __builtin_amdgcn_readfirstlane(tid >> 6);   // wave id 0..3
    int l15  = lane & 15, quad = lane >> 4;
    int cl   = tid & 31, xh = tid >> 5;                    // staging mapping

    f32x4 acc[4][2];
    #pragma unroll
    for (int mt = 0; mt < 4; ++mt)
        #pragma unroll
        for (int nt = 0; nt < 2; ++nt)
            acc[mt][nt] = (f32x4){0.f, 0.f, 0.f, 0.f};

    for (int kk = 0; kk < 9; ++kk) {
        __syncthreads();   // protect LDS tiles from previous chunk's readers
        // ---- stage w chunk: 128o x 128c bf16, 16B coalesced ----
        const uint4* wsrc = (const uint4*)(wt + (size_t)kk * OO * CC);
        #pragma unroll
        for (int j = 0; j < 8; ++j) {
            int idx = j * 256 + tid;
            int cs = idx & 15, o = idx >> 4;      // cs: 8-bf16 segment
            *(uint4*)&wl[o * 136 + cs * 8] = wsrc[idx];
        }
        // ---- gather v chunk: 64x x 128c; 32 lanes x float4 = one tap row ----
        #pragma unroll
        for (int j = 0; j < 8; ++j) {
            int xx = xh * 8 + j;
            int e = (kk << 6) + xx;
            float w0 = pw[e * 4 + 0], w1 = pw[e * 4 + 1];
            float w2 = pw[e * 4 + 2], w3 = pw[e * 4 + 3];
            float4 t0 = *(const float4*)(hb + pidx[e * 4 + 0] + cl * 4);
            float4 t1 = *(const float4*)(hb + pidx[e * 4 + 1] + cl * 4);
            float4 t2 = *(const float4*)(hb + pidx[e * 4 + 2] + cl * 4);
            float4 t3 = *(const float4*)(hb + pidx[e * 4 + 3] + cl * 4);
            float rx = w0 * t0.x + w1 * t1.x + w2 * t2.x + w3 * t3.x;
            float ry = w0 * t0.y + w1 * t1.y + w2 * t2.y + w3 * t3.y;
            float rz = w0 * t0.z + w1 * t1.z + w2 * t2.z + w3 * t3.z;
            float rw = w0 * t0.w + w1 * t1.w + w2 * t2.w + w3 * t3.w;
            bf16x4 pk = {(__bf16)rx, (__bf16)ry, (__bf16)rz, (__bf16)rw};
            *(bf16x4*)&vt[xx * 136 + cl * 4] = pk;
        }
        __syncthreads();
        // ---- MFMA: 4 K-steps of 32; wave covers 64x x 32o ----
        #pragma unroll
        for (int ks = 0; ks < 4; ++ks) {
            int kb = ks * 32 + quad * 8;
            bf16x8 a0 = *(const bf16x8*)&vt[(0 * 16 + l15) * 136 + kb];
            bf16x8 a1 = *(const bf16x8*)&vt[(1 * 16 + l15) * 136 + kb];
            bf16x8 a2 = *(const bf16x8*)&vt[(2 * 16 + l15) * 136 + kb];
            bf16x8 a3 = *(const bf16x8*)&vt[(3 * 16 + l15) * 136 + kb];
            bf16x8 b0 = *(const bf16x8*)&wl[(wv * 32 + l15) * 136 + kb];
            bf16x8 b1 = *(const bf16x8*)&wl[(wv * 32 + 16 + l15) * 136 + kb];
            acc[0][0] = __builtin_amdgcn_mfma_f32_16x16x32_bf16(a0, b0, acc[0][0], 0, 0, 0);
            acc[1][0] = __builtin_amdgcn_mfma_f32_16x16x32_bf16(a1, b0, acc[1][0], 0, 0, 0);
            acc[2][0] = __builtin_amdgcn_mfma_f32_16x16x32_bf16(a2, b0, acc[2][0], 0, 0, 0);
            acc[3][0] = __builtin_amdgcn_mfma_f32_16x16x32_bf16(a3, b0, acc[3][0], 0, 0, 0);
            acc[0][1] = __builtin_amdgcn_mfma_f32_16x16x32_bf16(a0, b1, acc[0][1], 0, 0, 0);
            acc[1][1] = __builtin_amdgcn_mfma_f32_16x16x32_bf16(a1, b1, acc[1][1], 0, 0, 0);
            acc[2][1] = __builtin_amdgcn_mfma_f32_16x16x32_bf16(a2, b1, acc[2][1], 0, 0, 0);
            acc[3][1] = __builtin_amdgcn_mfma_f32_16x16x32_bf16(a3, b1, acc[3][1], 0, 0, 0);
        }
    }

    // ---- epilogue: D row(m=x)=quad*4+reg, col(n=o)=l15; float4 per tile ----
    size_t ob = (size_t)b * OO * HW + (size_t)y * WW;
    #pragma unroll
    for (int nt = 0; nt < 2; ++nt) {
        int o = wv * 32 + nt * 16 + l15;
        float bias = b_dconv[o];
        #pragma unroll
        for (int mt = 0; mt < 4; ++mt) {
            int xb = mt * 16 + quad * 4;
            float4 r;
            r.x = acc[mt][nt][0] + bias;
            r.y = acc[mt][nt][1] + bias;
            r.z = acc[mt][nt][2] + bias;
            r.w = acc[mt][nt][3] + bias;
            *(float4*)&out[ob + (size_t)o * HW + xb] = r;
        }
    }
}

// ---------------------------------------------------------------------------
extern "C" void kernel_launch(void* const* d_in, const int* in_sizes, int n_in,
                              void* d_out, int out_size, void* d_ws, size_t ws_size,
                              hipStream_t stream)
{
    const float* x       = (const float*)d_in[0];
    const float* gamma   = (const float*)d_in[1];
    const float* beta    = (const float*)d_in[2];
    const float* mean    = (const float*)d_in[3];
    const float* var     = (const float*)d_in[4];
    const float* w_off   = (const float*)d_in[5];
    const float* b_off   = (const float*)d_in[6];
    const float* w_dconv = (const float*)d_in[7];
    const float* b_dconv = (const float*)d_in[8];
    float* out = (float*)d_out;

    char* ws = (char*)d_ws;
    float*  h_nchw  = (float*)ws;                          // 16,777,216 B
    float*  h_nhwc  = (float*)(ws + 16777216);             // 16,777,216 B
    float*  offs    = (float*)(ws + 33554432);             //  2,359,296 B
    __bf16* wt_bf   = (__bf16*)(ws + 35913728);            //    294,912 B
    float*  w_off_t = (float*)(ws + 36208640);             //     82,944 B

    transform_weights<<<576, 256, 0, stream>>>(w_dconv, w_off, wt_bf, w_off_t);
    bn_relu_transpose<<<512, 256, 0, stream>>>(x, gamma, beta, mean, var, h_nchw, h_nhwc);
    offset_conv<<<512, 256, 0, stream>>>(h_nchw, w_off_t, b_off, offs);
    deform_conv_mfma<<<512, 256, 0, stream>>>(h_nhwc, offs, wt_bf, b_dconv, out);
}

// Round 3
// 135.032 us; speedup vs baseline: 2.4053x; 1.3207x over previous
//
#include <hip/hip_runtime.h>

#define BB 8
#define CC 128
#define OO 128
#define HH 64
#define WW 64
#define HW (HH*WW)

typedef __attribute__((ext_vector_type(8))) __bf16 bf16x8;
typedef __attribute__((ext_vector_type(4))) __bf16 bf16x4;
typedef __attribute__((ext_vector_type(4))) float  f32x4;

// ---------------------------------------------------------------------------
// One-time weight relayouts (bf16):
//   wt_bf[kk][o][c]    <- w_dconv[o][c][kk]        (deform B-operand)
//   w_off_b[kk][o<32][c] <- w_off[o][c][ky][kx]    (offset B-operand, pad 18->32)
// ---------------------------------------------------------------------------
__global__ __launch_bounds__(256) void transform_weights(
    const float* __restrict__ w_dconv,
    const float* __restrict__ w_off,
    __bf16* __restrict__ wt_bf,
    __bf16* __restrict__ w_off_b)
{
    int idx = blockIdx.x * 256 + threadIdx.x;
    if (idx < 9 * 128 * 128) {
        int c  = idx & 127;
        int o  = (idx >> 7) & 127;
        int kk = idx >> 14;
        wt_bf[idx] = (__bf16)w_dconv[(o * 128 + c) * 9 + kk];
    }
    if (idx < 9 * 32 * 128) {
        int c  = idx & 127;
        int o  = (idx >> 7) & 31;
        int kk = idx >> 12;
        float v = (o < 18) ? w_off[o * 1152 + c * 9 + kk] : 0.f;
        w_off_b[idx] = (__bf16)v;
    }
}

// ---------------------------------------------------------------------------
// BN + ReLU -> h in NHWC bf16 (the only h layout kept).
// Block per (b,y), XCD-swizzled: b = blk&7 so each XCD owns one batch slice.
// float4 global reads, LDS transpose (bf16, stride 130: ~2-way banks max).
// ---------------------------------------------------------------------------
__global__ __launch_bounds__(256) void bn_relu_nhwc(
    const float* __restrict__ x,
    const float* __restrict__ gamma, const float* __restrict__ beta,
    const float* __restrict__ mean,  const float* __restrict__ var,
    __bf16* __restrict__ h)            // [b][y][x][c]
{
    __shared__ float inv_s[128], bb_s[128];
    __shared__ __bf16 tile[64 * 130];
    int blk = blockIdx.x;
    int b = blk & 7, y = blk >> 3;
    int tid = threadIdx.x;

    if (tid < 128) {
        float iv = gamma[tid] * rsqrtf(var[tid] + 1e-5f);
        inv_s[tid] = iv;
        bb_s[tid]  = beta[tid] - mean[tid] * iv;
    }
    __syncthreads();

    const float* xb = x + (size_t)b * CC * HW + (size_t)y * WW;
    #pragma unroll
    for (int i = 0; i < 8; ++i) {
        int idx = i * 256 + tid;          // over 128c x 16 x-quads
        int c = idx >> 4, x4 = idx & 15;
        float4 v = *(const float4*)(xb + (size_t)c * HW + x4 * 4);
        float iv = inv_s[c], bb = bb_s[c];
        tile[(x4 * 4 + 0) * 130 + c] = (__bf16)fmaxf(v.x * iv + bb, 0.f);
        tile[(x4 * 4 + 1) * 130 + c] = (__bf16)fmaxf(v.y * iv + bb, 0.f);
        tile[(x4 * 4 + 2) * 130 + c] = (__bf16)fmaxf(v.z * iv + bb, 0.f);
        tile[(x4 * 4 + 3) * 130 + c] = (__bf16)fmaxf(v.w * iv + bb, 0.f);
    }
    __syncthreads();

    __bf16* hb = h + ((size_t)b * HW + (size_t)y * WW) * CC;
    #pragma unroll
    for (int i = 0; i < 2; ++i) {
        int idx = i * 256 + tid;          // over 64x x 8 c16-groups
        int xx = idx >> 3, c16 = idx & 7;
        const uint* src = (const uint*)&tile[xx * 130 + c16 * 16];
        uint r0 = src[0], r1 = src[1], r2 = src[2], r3 = src[3];
        uint r4 = src[4], r5 = src[5], r6 = src[6], r7 = src[7];
        uint* dst = (uint*)(hb + (size_t)xx * CC + c16 * 16);
        *(uint4*)dst       = (uint4){r0, r1, r2, r3};
        *(uint4*)(dst + 4) = (uint4){r4, r5, r6, r7};
    }
}

// ---------------------------------------------------------------------------
// Offset conv as bf16 MFMA GEMM: per (b,y) block, 64x x 32oc x 1152k.
// A-chunk per kk: fixed-shift rows of h (zero-masked), c-contiguous bf16x8.
// Same verified fragment layouts as deform.
// ---------------------------------------------------------------------------
__global__ __launch_bounds__(256) void offset_mfma(
    const __bf16* __restrict__ h,       // [b][y][x][c]
    const __bf16* __restrict__ w_off_b, // [kk][32][128]
    const float* __restrict__ b_off,
    float* __restrict__ offs)           // [b][18][y][x]
{
    __shared__ __align__(16) __bf16 at[64 * 136];
    __shared__ __align__(16) __bf16 bt[32 * 136];
    int blk = blockIdx.x;
    int b = blk & 7, y = blk >> 3;
    int tid = threadIdx.x;
    int lane = tid & 63;
    int wv  = __builtin_amdgcn_readfirstlane(tid >> 6);
    int l15 = lane & 15, quad = lane >> 4;

    const __bf16* hb = h + (size_t)b * HW * CC;

    f32x4 acc[2];
    acc[0] = (f32x4){0.f, 0.f, 0.f, 0.f};
    acc[1] = (f32x4){0.f, 0.f, 0.f, 0.f};

    for (int kk = 0; kk < 9; ++kk) {
        int dy = kk / 3 - 1, dx = kk % 3 - 1;
        int yy = y + dy;
        bool yok = (yy >= 0) && (yy < HH);
        __syncthreads();
        // stage A: 64x x 128c bf16
        #pragma unroll
        for (int i = 0; i < 4; ++i) {
            int idx = i * 256 + tid;
            int xx = idx >> 4, c8 = idx & 15;
            int xs = xx + dx;
            uint4 v = (uint4){0u, 0u, 0u, 0u};
            if (yok && xs >= 0 && xs < WW)
                v = *(const uint4*)(hb + ((size_t)yy * WW + xs) * CC + c8 * 8);
            *(uint4*)&at[xx * 136 + c8 * 8] = v;
        }
        // stage B: 32o x 128c bf16
        const __bf16* wsrc = w_off_b + (size_t)kk * 32 * 128;
        #pragma unroll
        for (int i = 0; i < 2; ++i) {
            int idx = i * 256 + tid;
            int o = idx >> 4, c8 = idx & 15;
            *(uint4*)&bt[o * 136 + c8 * 8] = *(const uint4*)(wsrc + o * 128 + c8 * 8);
        }
        __syncthreads();
        #pragma unroll
        for (int ks = 0; ks < 4; ++ks) {
            int kb = ks * 32 + quad * 8;
            bf16x8 a  = *(const bf16x8*)&at[(wv * 16 + l15) * 136 + kb];
            bf16x8 b0 = *(const bf16x8*)&bt[l15 * 136 + kb];
            bf16x8 b1 = *(const bf16x8*)&bt[(16 + l15) * 136 + kb];
            acc[0] = __builtin_amdgcn_mfma_f32_16x16x32_bf16(a, b0, acc[0], 0, 0, 0);
            acc[1] = __builtin_amdgcn_mfma_f32_16x16x32_bf16(a, b1, acc[1], 0, 0, 0);
        }
    }

    size_t ob = (size_t)b * 18 * HW + (size_t)y * WW;
    #pragma unroll
    for (int nt = 0; nt < 2; ++nt) {
        int oc = nt * 16 + l15;
        if (oc < 18) {
            float bias = b_off[oc];
            #pragma unroll
            for (int r = 0; r < 4; ++r) {
                int xx = wv * 16 + quad * 4 + r;
                offs[ob + (size_t)oc * HW + xx] = acc[nt][r] + bias;
            }
        }
    }
}

// ---------------------------------------------------------------------------
// Deformable conv via bf16 MFMA. Block per (b,y), XCD-swizzled (b = blk&7):
// all gathers for one batch hit one XCD's L2 (2MB slice in 4MB L2).
// h is bf16 NHWC -> tap loads are bf16x4 (half the L2 bytes of round 2).
// ---------------------------------------------------------------------------
__global__ __launch_bounds__(256, 2) void deform_conv_mfma(
    const __bf16* __restrict__ h,      // [b][y][x][c] bf16
    const float* __restrict__ offs,    // [b][18][y][x]
    const __bf16* __restrict__ wt,     // [kk][o][c] bf16
    const float* __restrict__ b_dconv,
    float* __restrict__ out)           // NCHW fp32
{
    __shared__ float pw[576 * 4];
    __shared__ int   pidx[576 * 4];
    __shared__ __align__(16) __bf16 vt[64 * 136];
    __shared__ __align__(16) __bf16 wl[128 * 136];

    int blk = blockIdx.x;
    int b = blk & 7, y = blk >> 3;
    int tid = threadIdx.x;

    const __bf16* hb = h + (size_t)b * HW * CC;
    size_t offbase = (size_t)b * 18 * HW + (size_t)y * WW;

    // ---- phase 0: bilinear params (masked weights + clamped tap offsets) ----
    for (int e = tid; e < 576; e += 256) {
        int kk = e >> 6, xx = e & 63;
        float dy = offs[offbase + (size_t)(2 * kk) * HW + xx];
        float dx = offs[offbase + (size_t)(2 * kk + 1) * HW + xx];
        float py = dy + (float)y + (float)(kk / 3 - 1);
        float px = dx + (float)xx + (float)(kk % 3 - 1);
        float fy = floorf(py), fx = floorf(px);
        int y0 = (int)fy, x0 = (int)fx;
        float wy = py - fy, wx = px - fx;
        int y1 = y0 + 1, x1 = x0 + 1;
        bool vy0 = (y0 >= 0) && (y0 < HH);
        bool vy1 = (y1 >= 0) && (y1 < HH);
        bool vx0 = (x0 >= 0) && (x0 < WW);
        bool vx1 = (x1 >= 0) && (x1 < WW);
        int yc0 = min(max(y0, 0), HH - 1), yc1 = min(max(y1, 0), HH - 1);
        int xc0 = min(max(x0, 0), WW - 1), xc1 = min(max(x1, 0), WW - 1);
        pw[e * 4 + 0] = (vy0 && vx0) ? (1.f - wy) * (1.f - wx) : 0.f;
        pw[e * 4 + 1] = (vy0 && vx1) ? (1.f - wy) * wx         : 0.f;
        pw[e * 4 + 2] = (vy1 && vx0) ? wy * (1.f - wx)         : 0.f;
        pw[e * 4 + 3] = (vy1 && vx1) ? wy * wx                 : 0.f;
        pidx[e * 4 + 0] = (yc0 * WW + xc0) * CC;
        pidx[e * 4 + 1] = (yc0 * WW + xc1) * CC;
        pidx[e * 4 + 2] = (yc1 * WW + xc0) * CC;
        pidx[e * 4 + 3] = (yc1 * WW + xc1) * CC;
    }

    int lane = tid & 63;
    int wv   = __builtin_amdgcn_readfirstlane(tid >> 6);
    int l15  = lane & 15, quad = lane >> 4;
    int cl   = tid & 31, xh = tid >> 5;

    f32x4 acc[4][2];
    #pragma unroll
    for (int mt = 0; mt < 4; ++mt)
        #pragma unroll
        for (int nt = 0; nt < 2; ++nt)
            acc[mt][nt] = (f32x4){0.f, 0.f, 0.f, 0.f};

    for (int kk = 0; kk < 9; ++kk) {
        __syncthreads();
        // ---- stage w chunk: 128o x 128c bf16, 16B coalesced ----
        const uint4* wsrc = (const uint4*)(wt + (size_t)kk * OO * CC);
        #pragma unroll
        for (int j = 0; j < 8; ++j) {
            int idx = j * 256 + tid;
            int cs = idx & 15, o = idx >> 4;
            *(uint4*)&wl[o * 136 + cs * 8] = wsrc[idx];
        }
        // ---- gather v chunk: 64x x 128c; bf16x4 taps, fp32 weighting ----
        #pragma unroll
        for (int j = 0; j < 8; ++j) {
            int xx = xh * 8 + j;
            int e = (kk << 6) + xx;
            float w0 = pw[e * 4 + 0], w1 = pw[e * 4 + 1];
            float w2 = pw[e * 4 + 2], w3 = pw[e * 4 + 3];
            bf16x4 t0 = *(const bf16x4*)(hb + pidx[e * 4 + 0] + cl * 4);
            bf16x4 t1 = *(const bf16x4*)(hb + pidx[e * 4 + 1] + cl * 4);
            bf16x4 t2 = *(const bf16x4*)(hb + pidx[e * 4 + 2] + cl * 4);
            bf16x4 t3 = *(const bf16x4*)(hb + pidx[e * 4 + 3] + cl * 4);
            float rx = w0 * (float)t0[0] + w1 * (float)t1[0] + w2 * (float)t2[0] + w3 * (float)t3[0];
            float ry = w0 * (float)t0[1] + w1 * (float)t1[1] + w2 * (float)t2[1] + w3 * (float)t3[1];
            float rz = w0 * (float)t0[2] + w1 * (float)t1[2] + w2 * (float)t2[2] + w3 * (float)t3[2];
            float rw = w0 * (float)t0[3] + w1 * (float)t1[3] + w2 * (float)t2[3] + w3 * (float)t3[3];
            bf16x4 pk = {(__bf16)rx, (__bf16)ry, (__bf16)rz, (__bf16)rw};
            *(bf16x4*)&vt[xx * 136 + cl * 4] = pk;
        }
        __syncthreads();
        // ---- MFMA: 4 K-steps of 32; wave covers 64x x 32o ----
        #pragma unroll
        for (int ks = 0; ks < 4; ++ks) {
            int kb = ks * 32 + quad * 8;
            bf16x8 a0 = *(const bf16x8*)&vt[(0 * 16 + l15) * 136 + kb];
            bf16x8 a1 = *(const bf16x8*)&vt[(1 * 16 + l15) * 136 + kb];
            bf16x8 a2 = *(const bf16x8*)&vt[(2 * 16 + l15) * 136 + kb];
            bf16x8 a3 = *(const bf16x8*)&vt[(3 * 16 + l15) * 136 + kb];
            bf16x8 b0 = *(const bf16x8*)&wl[(wv * 32 + l15) * 136 + kb];
            bf16x8 b1 = *(const bf16x8*)&wl[(wv * 32 + 16 + l15) * 136 + kb];
            acc[0][0] = __builtin_amdgcn_mfma_f32_16x16x32_bf16(a0, b0, acc[0][0], 0, 0, 0);
            acc[1][0] = __builtin_amdgcn_mfma_f32_16x16x32_bf16(a1, b0, acc[1][0], 0, 0, 0);
            acc[2][0] = __builtin_amdgcn_mfma_f32_16x16x32_bf16(a2, b0, acc[2][0], 0, 0, 0);
            acc[3][0] = __builtin_amdgcn_mfma_f32_16x16x32_bf16(a3, b0, acc[3][0], 0, 0, 0);
            acc[0][1] = __builtin_amdgcn_mfma_f32_16x16x32_bf16(a0, b1, acc[0][1], 0, 0, 0);
            acc[1][1] = __builtin_amdgcn_mfma_f32_16x16x32_bf16(a1, b1, acc[1][1], 0, 0, 0);
            acc[2][1] = __builtin_amdgcn_mfma_f32_16x16x32_bf16(a2, b1, acc[2][1], 0, 0, 0);
            acc[3][1] = __builtin_amdgcn_mfma_f32_16x16x32_bf16(a3, b1, acc[3][1], 0, 0, 0);
        }
    }

    size_t ob = (size_t)b * OO * HW + (size_t)y * WW;
    #pragma unroll
    for (int nt = 0; nt < 2; ++nt) {
        int o = wv * 32 + nt * 16 + l15;
        float bias = b_dconv[o];
        #pragma unroll
        for (int mt = 0; mt < 4; ++mt) {
            int xb = mt * 16 + quad * 4;
            float4 r;
            r.x = acc[mt][nt][0] + bias;
            r.y = acc[mt][nt][1] + bias;
            r.z = acc[mt][nt][2] + bias;
            r.w = acc[mt][nt][3] + bias;
            *(float4*)&out[ob + (size_t)o * HW + xb] = r;
        }
    }
}

// ---------------------------------------------------------------------------
extern "C" void kernel_launch(void* const* d_in, const int* in_sizes, int n_in,
                              void* d_out, int out_size, void* d_ws, size_t ws_size,
                              hipStream_t stream)
{
    const float* x       = (const float*)d_in[0];
    const float* gamma   = (const float*)d_in[1];
    const float* beta    = (const float*)d_in[2];
    const float* mean    = (const float*)d_in[3];
    const float* var     = (const float*)d_in[4];
    const float* w_off   = (const float*)d_in[5];
    const float* b_off   = (const float*)d_in[6];
    const float* w_dconv = (const float*)d_in[7];
    const float* b_dconv = (const float*)d_in[8];
    float* out = (float*)d_out;

    char* ws = (char*)d_ws;
    __bf16* h_bf    = (__bf16*)ws;                 // 8,388,608 B
    float*  offs    = (float*)(ws + 8388608);      // 2,359,296 B
    __bf16* wt_bf   = (__bf16*)(ws + 10747904);    //   294,912 B
    __bf16* w_off_b = (__bf16*)(ws + 11042816);    //    73,728 B

    transform_weights<<<576, 256, 0, stream>>>(w_dconv, w_off, wt_bf, w_off_b);
    bn_relu_nhwc<<<512, 256, 0, stream>>>(x, gamma, beta, mean, var, h_bf);
    offset_mfma<<<512, 256, 0, stream>>>(h_bf, w_off_b, b_off, offs);
    deform_conv_mfma<<<512, 256, 0, stream>>>(h_bf, offs, wt_bf, b_dconv, out);
}